// Round 5
// baseline (406.679 us; speedup 1.0000x reference)
//
#include <hip/hip_runtime.h>
#include <cmath>

#define M_ROWS  65536
#define D_DIM   64
#define K_CODES 4096

// d_out float offsets (z_q_st | indices | vq_loss | perplexity | z_q)
#define OFF_IDX  4194304
#define OFF_SCAL 4259840
#define OFF_ZQ   4259842

// scratch regions inside d_out
#define IMG_OFF   (4u << 20)                 // codebook image, 1.15 MB (in z_q_st region, consumed before it's written)
#define E2B_OFF   (IMG_OFF + 1179648u)       // e2+32 array, 16 KB
#define CANDB_OFF 17039368u                  // == OFF_ZQ*4 : candidate lists, 4 MB (overwritten by copy_zq at the end)

// codebook chunk image: 128 codes, bf16 hi/lo split, row stride 144 B (bank skew)
#define ROWB     144
#define CH_LO    18432                        // 128*144
#define CH_BYTES 36864                        // hi + lo
#define CH_QUADS 2304                         // CH_BYTES/16, == 9*256
#define NSPLIT   4
#define NCHB     8                            // chunks per block (1024 codes)

typedef __attribute__((ext_vector_type(8))) short s16x8;
typedef __attribute__((ext_vector_type(4))) float f32x4;

__device__ __forceinline__ unsigned short f2bf(float f) {   // RNE float->bf16 bits
  unsigned int u = __float_as_uint(f);
  return (unsigned short)((u + 0x7FFFu + ((u >> 16) & 1u)) >> 16);
}
__device__ __forceinline__ float bf2f(unsigned short h) {
  return __uint_as_float(((unsigned int)h) << 16);
}
__device__ __forceinline__ unsigned int umin_(unsigned int a, unsigned int b) {
  return a < b ? a : b;
}
// second-min update: with invariant b1 <= b2, new b2 = median(b1, b2, key)
__device__ __forceinline__ unsigned int med3_u32(unsigned int a, unsigned int b, unsigned int c) {
  unsigned int d;
  asm("v_med3_u32 %0, %1, %2, %3" : "=v"(d) : "v"(a), "v"(b), "v"(c));
  return d;
}

// ---------------------------------------------------------------------------
// K1: e2[k] (numpy-pairwise exact) + bf16 hi/lo split image + (e2+32) array
// ---------------------------------------------------------------------------
__global__ void split_cb_kernel(const float* __restrict__ cb,
                                float* __restrict__ e2,
                                char* __restrict__ img,
                                float* __restrict__ e2b) {
  int k = blockIdx.x * 256 + threadIdx.x;
  if (k >= K_CODES) return;
  const float* row = cb + (size_t)k * D_DIM;
  float s;
  {
#pragma clang fp contract(off)
    float r0, r1, r2, r3, r4, r5, r6, r7;
    {
      float v0 = row[0], v1 = row[1], v2 = row[2], v3 = row[3];
      float v4 = row[4], v5 = row[5], v6 = row[6], v7 = row[7];
      r0 = v0 * v0; r1 = v1 * v1; r2 = v2 * v2; r3 = v3 * v3;
      r4 = v4 * v4; r5 = v5 * v5; r6 = v6 * v6; r7 = v7 * v7;
    }
#pragma unroll
    for (int i = 8; i < 64; i += 8) {
      float v0 = row[i + 0], v1 = row[i + 1], v2 = row[i + 2], v3 = row[i + 3];
      float v4 = row[i + 4], v5 = row[i + 5], v6 = row[i + 6], v7 = row[i + 7];
      r0 = r0 + v0 * v0; r1 = r1 + v1 * v1; r2 = r2 + v2 * v2; r3 = r3 + v3 * v3;
      r4 = r4 + v4 * v4; r5 = r5 + v5 * v5; r6 = r6 + v6 * v6; r7 = r7 + v7 * v7;
    }
    s = ((r0 + r1) + (r2 + r3)) + ((r4 + r5) + (r6 + r7));
  }
  e2[k] = s;
  e2b[k] = s + 32.0f;                         // bias keeps key values positive

  int c = k >> 7, r = k & 127;
  char* base = img + (size_t)c * CH_BYTES;
  unsigned short* hi = (unsigned short*)(base + r * ROWB);
  unsigned short* lo = (unsigned short*)(base + CH_LO + r * ROWB);
#pragma unroll
  for (int d = 0; d < 64; ++d) {
    float f = row[d];
    unsigned short h = f2bf(f);
    hi[d] = h;
    lo[d] = f2bf(f - bf2f(h));
  }
#pragma unroll
  for (int d = 64; d < 72; ++d) { hi[d] = 0; lo[d] = 0; }
}

// ---------------------------------------------------------------------------
// K2: MFMA distance pass, K-split by 4. Each wave = 64 rows (mt=4); each block
// = 256 rows x 1024 codes. val = (e2+32) - 2 z.e via 3 bf16-split products,
// e2 broadcast as read-only MFMA C-input (D != C, no per-mt copies).
// Sortable key = v_and_or(bits, ~0xFF, tile); top-2 via min + v_med3_u32.
// Per-row top-4-of-32 -> cands[row*16 + split*4 + i].
// ---------------------------------------------------------------------------
__global__ __launch_bounds__(256, 4)
void vq_mfma_kernel(const float* __restrict__ z_e,
                    const char* __restrict__ img,
                    const float* __restrict__ e2b,
                    unsigned int* __restrict__ cands) {
  __shared__ union {
    char raw[CH_BYTES];
    uint4 q[CH_QUADS];
    unsigned int cand[256 * 32];
  } sm;
  const int tid  = threadIdx.x;
  const int wave = tid >> 6, lane = tid & 63;
  const int quad = lane >> 4, c16 = lane & 15;
  const int rb   = blockIdx.x >> 2;           // row-group of 256
  const int sp   = blockIdx.x & 3;            // K-split id
  const int mb   = rb * 256 + wave * 64;

  // A-fragments: 4 row-tiles x (k-halves) x (hi/lo), A[m=lane&15][k=quad*8+j]
  s16x8 zh[4][2], zl[4][2];
#pragma unroll
  for (int mt = 0; mt < 4; ++mt) {
    int m = mb + mt * 16 + c16;
#pragma unroll
    for (int s = 0; s < 2; ++s) {
      const float* zp = z_e + (size_t)m * 64 + s * 32 + quad * 8;
      float4 fa = ((const float4*)zp)[0];
      float4 fb = ((const float4*)zp)[1];
      float v[8] = {fa.x, fa.y, fa.z, fa.w, fb.x, fb.y, fb.z, fb.w};
      union { s16x8 v8; unsigned short e[8]; } H, L;
#pragma unroll
      for (int j = 0; j < 8; ++j) {
        float f = -2.0f * v[j];
        unsigned short h = f2bf(f);
        H.e[j] = h;
        L.e[j] = f2bf(f - bf2f(h));
      }
      zh[mt][s] = H.v8;
      zl[mt][s] = L.v8;
    }
  }

  unsigned int b1[4][4], b2[4][4];
#pragma unroll
  for (int mt = 0; mt < 4; ++mt)
#pragma unroll
    for (int r = 0; r < 4; ++r) { b1[mt][r] = 0xFFFFFFFFu; b2[mt][r] = 0xFFFFFFFFu; }

  for (int c = 0; c < NCHB; ++c) {
    __syncthreads();
    {
      const uint4* src = (const uint4*)(img + (size_t)(sp * NCHB + c) * CH_BYTES);
#pragma unroll
      for (int i = 0; i < 9; ++i) sm.q[tid + i * 256] = src[tid + i * 256];
    }
    __syncthreads();

#pragma unroll
    for (int t = 0; t < 8; ++t) {
      float e2v = e2b[sp * 1024 + c * 128 + t * 16 + c16];
      const char* hrow = sm.raw + (t * 16 + c16) * ROWB;
      s16x8 Bh0 = *(const s16x8*)(hrow + quad * 16);
      s16x8 Bh1 = *(const s16x8*)(hrow + 64 + quad * 16);
      s16x8 Bl0 = *(const s16x8*)(hrow + CH_LO + quad * 16);
      s16x8 Bl1 = *(const s16x8*)(hrow + CH_LO + 64 + quad * 16);
      unsigned int tid8 = (unsigned int)(sp * 64 + c * 8 + t);  // global 16-code tile id
      f32x4 cvec = {e2v, e2v, e2v, e2v};      // read-only C operand, shared by all mt

#pragma unroll
      for (int mt = 0; mt < 4; ++mt) {
        f32x4 acc;
        acc = __builtin_amdgcn_mfma_f32_16x16x32_bf16(zh[mt][0], Bh0, cvec, 0, 0, 0);
        acc = __builtin_amdgcn_mfma_f32_16x16x32_bf16(zh[mt][1], Bh1, acc, 0, 0, 0);
        acc = __builtin_amdgcn_mfma_f32_16x16x32_bf16(zl[mt][0], Bh0, acc, 0, 0, 0);
        acc = __builtin_amdgcn_mfma_f32_16x16x32_bf16(zl[mt][1], Bh1, acc, 0, 0, 0);
        acc = __builtin_amdgcn_mfma_f32_16x16x32_bf16(zh[mt][0], Bl0, acc, 0, 0, 0);
        acc = __builtin_amdgcn_mfma_f32_16x16x32_bf16(zh[mt][1], Bl1, acc, 0, 0, 0);
#pragma unroll
        for (int r = 0; r < 4; ++r) {
          unsigned int key = (__float_as_uint(acc[r]) & 0xFFFFFF00u) | tid8;  // v_and_or_b32
          b2[mt][r] = med3_u32(b1[mt][r], b2[mt][r], key);   // 2nd-min update (old b1)
          b1[mt][r] = umin_(b1[mt][r], key);
        }
      }
    }
  }

  __syncthreads();   // reuse sm as candidate buffer
#pragma unroll
  for (int mt = 0; mt < 4; ++mt)
#pragma unroll
    for (int r = 0; r < 4; ++r) {
      int row = wave * 64 + mt * 16 + quad * 4 + r;   // C: col=lane&15, row=quad*4+reg
      sm.cand[row * 32 + c16 * 2 + 0] = b1[mt][r];
      sm.cand[row * 32 + c16 * 2 + 1] = b2[mt][r];
    }
  __syncthreads();

  {
    unsigned int kk[4] = {0xFFFFFFFFu, 0xFFFFFFFFu, 0xFFFFFFFFu, 0xFFFFFFFFu};
    unsigned int vv[4] = {0, 0, 0, 0};
    for (int j = 0; j < 32; ++j) {
      unsigned int key = sm.cand[tid * 32 + j];
      if (key < kk[3]) {
        kk[3] = key;
        vv[3] = (key & 0xFFu) * 16 + (unsigned int)(j >> 1);  // k = tile*16 + col
        for (int p = 3; p > 0; --p)
          if (kk[p] < kk[p - 1]) {
            unsigned int a = kk[p]; kk[p] = kk[p - 1]; kk[p - 1] = a;
            unsigned int b = vv[p]; vv[p] = vv[p - 1]; vv[p - 1] = b;
          }
      }
    }
    int grow = rb * 256 + tid;
#pragma unroll
    for (int i = 0; i < 4; ++i) cands[grow * 16 + sp * 4 + i] = vv[i];
  }
}

// ---------------------------------------------------------------------------
// K3: exact re-check of 16 candidates/row, 16 lanes per row (one cand each).
// z rows staged once in LDS (stride 68 floats -> conflict-free broadcast).
// numpy-exact formula, first-min tie-break. Writes idx + z_q_st + loss accum.
// ---------------------------------------------------------------------------
__global__ __launch_bounds__(256)
void exact_pick_kernel(const float* __restrict__ z_e, const float* __restrict__ cb,
                       const float* __restrict__ e2, const unsigned int* __restrict__ cands,
                       float* __restrict__ out, double* __restrict__ accum) {
  __shared__ float lds_z[16 * 68];
  __shared__ double lds_red[4];
  const int tid = threadIdx.x;
  const int rl  = tid >> 4;                       // row local 0..15
  const int j   = tid & 15;                       // candidate slot / element group
  const int r   = blockIdx.x * 16 + rl;           // global row

  // stage 16 z rows (coalesced): thread t copies float4 #t
  {
    float4 v = ((const float4*)z_e)[(size_t)blockIdx.x * 256 + tid];
    *(float4*)&lds_z[(tid >> 4) * 68 + (tid & 15) * 4] = v;
  }
  __syncthreads();

  const float* zrow = &lds_z[rl * 68];
  float4 z4[16];
#pragma unroll
  for (int i = 0; i < 16; ++i) z4[i] = *(const float4*)&zrow[i * 4];

  float z2;
  {
#pragma clang fp contract(off)
    float4 R0 = make_float4(0.f, 0.f, 0.f, 0.f);
    float4 R1 = make_float4(0.f, 0.f, 0.f, 0.f);
#pragma unroll
    for (int a = 0; a < 16; a += 2) {
      R0.x = R0.x + z4[a].x * z4[a].x;
      R0.y = R0.y + z4[a].y * z4[a].y;
      R0.z = R0.z + z4[a].z * z4[a].z;
      R0.w = R0.w + z4[a].w * z4[a].w;
      R1.x = R1.x + z4[a + 1].x * z4[a + 1].x;
      R1.y = R1.y + z4[a + 1].y * z4[a + 1].y;
      R1.z = R1.z + z4[a + 1].z * z4[a + 1].z;
      R1.w = R1.w + z4[a + 1].w * z4[a + 1].w;
    }
    z2 = ((R0.x + R0.y) + (R0.z + R0.w)) + ((R1.x + R1.y) + (R1.z + R1.w));
  }

  // each lane: exact distance of its candidate
  int k = (int)cands[(size_t)r * 16 + j];
  float d;
  {
    const float4* ev = (const float4*)(cb + (size_t)k * 64);
    float4 a0 = make_float4(0.f, 0.f, 0.f, 0.f);
    float4 a1 = make_float4(0.f, 0.f, 0.f, 0.f);
    float4 a2 = make_float4(0.f, 0.f, 0.f, 0.f);
    float4 a3 = make_float4(0.f, 0.f, 0.f, 0.f);
#pragma unroll
    for (int q = 0; q < 4; ++q) {
      float4 e0 = ev[4 * q + 0], e1 = ev[4 * q + 1], e2v = ev[4 * q + 2], e3 = ev[4 * q + 3];
      a0.x = fmaf(z4[4 * q + 0].x, e0.x, a0.x); a0.y = fmaf(z4[4 * q + 0].y, e0.y, a0.y);
      a0.z = fmaf(z4[4 * q + 0].z, e0.z, a0.z); a0.w = fmaf(z4[4 * q + 0].w, e0.w, a0.w);
      a1.x = fmaf(z4[4 * q + 1].x, e1.x, a1.x); a1.y = fmaf(z4[4 * q + 1].y, e1.y, a1.y);
      a1.z = fmaf(z4[4 * q + 1].z, e1.z, a1.z); a1.w = fmaf(z4[4 * q + 1].w, e1.w, a1.w);
      a2.x = fmaf(z4[4 * q + 2].x, e2v.x, a2.x); a2.y = fmaf(z4[4 * q + 2].y, e2v.y, a2.y);
      a2.z = fmaf(z4[4 * q + 2].z, e2v.z, a2.z); a2.w = fmaf(z4[4 * q + 2].w, e2v.w, a2.w);
      a3.x = fmaf(z4[4 * q + 3].x, e3.x, a3.x); a3.y = fmaf(z4[4 * q + 3].y, e3.y, a3.y);
      a3.z = fmaf(z4[4 * q + 3].z, e3.z, a3.z); a3.w = fmaf(z4[4 * q + 3].w, e3.w, a3.w);
    }
    {
#pragma clang fp contract(off)
      float sx = (a0.x + a1.x) + (a2.x + a3.x);
      float sy = (a0.y + a1.y) + (a2.y + a3.y);
      float sz = (a0.z + a1.z) + (a2.z + a3.z);
      float sw = (a0.w + a1.w) + (a2.w + a3.w);
      float dot = (sx + sy) + (sz + sw);
      float tt = z2 + e2[k];
      d = tt - 2.0f * dot;
    }
  }

  // min over 16 lanes, tie -> smaller k (numpy first-occurrence)
#pragma unroll
  for (int off = 8; off > 0; off >>= 1) {
    float d2 = __shfl_down(d, off, 16);
    int   k2 = __shfl_down(k, off, 16);
    if (d2 < d || (d2 == d && k2 < k)) { d = d2; k = k2; }
  }
  int bk = __shfl(k, 0, 16);

  if (j == 0) out[OFF_IDX + r] = (float)bk;

  // lane j writes elements 4j..4j+3 of z_q_st; partial commit loss
  float4 q  = ((const float4*)(cb + (size_t)bk * 64))[j];
  float4 zv = *(const float4*)&zrow[j * 4];
  ((float4*)(out + (size_t)r * 64))[j] = q;
  double csum;
  {
    float dx = zv.x - q.x, dy = zv.y - q.y, dz = zv.z - q.z, dw = zv.w - q.w;
    csum = (double)dx * dx + (double)dy * dy + (double)dz * dz + (double)dw * dw;
  }
#pragma unroll
  for (int off = 32; off > 0; off >>= 1) csum += __shfl_down(csum, off);
  if ((tid & 63) == 0) lds_red[tid >> 6] = csum;
  __syncthreads();
  if (tid == 0)
    atomicAdd(accum, (lds_red[0] + lds_red[1]) + (lds_red[2] + lds_red[3]));
}

// ---------------------------------------------------------------------------
// K4: z_q <- z_q_st (identical values); also overwrites the cand scratch.
// ---------------------------------------------------------------------------
__global__ void copy_zq_kernel(float* __restrict__ out) {
  size_t t = (size_t)blockIdx.x * 256 + threadIdx.x;   // 1M threads, one float4 each
  float4 v = ((const float4*)out)[t];
  float* dst = out + OFF_ZQ + t * 4;                   // 8B-aligned only
  ((float2*)dst)[0] = make_float2(v.x, v.y);
  ((float2*)dst)[1] = make_float2(v.z, v.w);
}

// ---------------------------------------------------------------------------
// K5: vq_loss + perplexity
// ---------------------------------------------------------------------------
__global__ void finalize_kernel(const float* __restrict__ ema,
                                const double* __restrict__ accum,
                                float* __restrict__ out) {
  __shared__ double red[256];
  const int t = threadIdx.x;

  double s = 0.0;
  for (int i = t; i < K_CODES; i += 256) s += (double)(ema[i] + 1e-10f);
  red[t] = s;
  __syncthreads();
  for (int off = 128; off > 0; off >>= 1) {
    if (t < off) red[t] += red[t + off];
    __syncthreads();
  }
  double S = red[0];
  __syncthreads();

  double h = 0.0;
  for (int i = t; i < K_CODES; i += 256) {
    float p = (float)((ema[i] + 1e-10f) / (float)S);
    h += (double)(p * logf(p));
  }
  red[t] = h;
  __syncthreads();
  for (int off = 128; off > 0; off >>= 1) {
    if (t < off) red[t] += red[t + off];
    __syncthreads();
  }

  if (t == 0) {
    out[OFF_SCAL]     = 0.25f * (float)(accum[0] / (double)((size_t)M_ROWS * (size_t)D_DIM));
    out[OFF_SCAL + 1] = expf((float)(-red[0]));
  }
}

extern "C" void kernel_launch(void* const* d_in, const int* in_sizes, int n_in,
                              void* d_out, int out_size, void* d_ws, size_t ws_size,
                              hipStream_t stream) {
  (void)in_sizes; (void)n_in; (void)out_size; (void)ws_size;
  const float* z_e = (const float*)d_in[0];
  const float* cb  = (const float*)d_in[1];
  const float* ema = (const float*)d_in[2];
  float* out = (float*)d_out;

  double* accum = (double*)d_ws;                            // 8 B used, 256 B zeroed
  float* e2     = (float*)((char*)d_ws + 256);              // K_CODES floats
  char*  img    = (char*)d_out + IMG_OFF;                   // 1.15 MB scratch
  float* e2b    = (float*)((char*)d_out + E2B_OFF);         // 16 KB scratch
  unsigned int* cands = (unsigned int*)((char*)d_out + CANDB_OFF);  // 4 MB scratch in z_q region

  (void)hipMemsetAsync(d_ws, 0, 256, stream);
  split_cb_kernel<<<K_CODES / 256, 256, 0, stream>>>(cb, e2, img, e2b);
  vq_mfma_kernel<<<(M_ROWS / 256) * NSPLIT, 256, 0, stream>>>(z_e, img, e2b, cands);
  exact_pick_kernel<<<M_ROWS / 16, 256, 0, stream>>>(z_e, cb, e2, cands, out, accum);
  copy_zq_kernel<<<(M_ROWS * D_DIM / 4) / 256, 256, 0, stream>>>(out);
  finalize_kernel<<<1, 256, 0, stream>>>(ema, accum, out);
}

// Round 6
// 251.431 us; speedup vs baseline: 1.6175x; 1.6175x over previous
//
#include <hip/hip_runtime.h>
#include <cmath>

#define M_ROWS  65536
#define D_DIM   64
#define K_CODES 4096

// d_out float offsets (z_q_st | indices | vq_loss | perplexity | z_q)
#define OFF_IDX  4194304
#define OFF_SCAL 4259840
#define OFF_ZQ   4259842

// scratch regions inside d_out (consumed before their region is written)
#define IMG_OFF   (4u << 20)                 // codebook image, 1 MB (in z_q_st region)
#define E2B_OFF   (IMG_OFF + 1048576u)       // e2+32 array, 16 KB
#define CANDB_OFF 17039368u                  // == OFF_ZQ*4 : fallback cand region (overwritten by copy_zq)

// codebook chunk image: 128 codes, bf16 hi/lo split, 128 B/row, XOR-swizzled granules
#define CH_LO    16384
#define CH_BYTES 32768
#define CH_QUADS 2048
#define NSPLIT   4
#define NCHB     8                            // chunks per block (1024 codes)

typedef __attribute__((ext_vector_type(8))) short s16x8;
typedef __attribute__((ext_vector_type(4))) float f32x4;

__device__ __forceinline__ unsigned short f2bf(float f) {   // RNE float->bf16 bits
  unsigned int u = __float_as_uint(f);
  return (unsigned short)((u + 0x7FFFu + ((u >> 16) & 1u)) >> 16);
}
__device__ __forceinline__ float bf2f(unsigned short h) {
  return __uint_as_float(((unsigned int)h) << 16);
}
__device__ __forceinline__ unsigned int umin_(unsigned int a, unsigned int b) {
  return a < b ? a : b;
}
// second-min update: with invariant b1 <= b2, new b2 = median(old b1, b2, key)
__device__ __forceinline__ unsigned int med3_u32(unsigned int a, unsigned int b, unsigned int c) {
  unsigned int d;
  asm("v_med3_u32 %0, %1, %2, %3" : "=v"(d) : "v"(a), "v"(b), "v"(c));
  return d;
}

// ---------------------------------------------------------------------------
// K1a: e2[k] exact (numpy pairwise pattern) + (e2+32) bias array
// ---------------------------------------------------------------------------
__global__ void e2_kernel(const float* __restrict__ cb,
                          float* __restrict__ e2, float* __restrict__ e2b) {
  int k = blockIdx.x * 256 + threadIdx.x;
  if (k >= K_CODES) return;
  const float* row = cb + (size_t)k * D_DIM;
  float s;
  {
#pragma clang fp contract(off)
    float r0, r1, r2, r3, r4, r5, r6, r7;
    {
      float v0 = row[0], v1 = row[1], v2 = row[2], v3 = row[3];
      float v4 = row[4], v5 = row[5], v6 = row[6], v7 = row[7];
      r0 = v0 * v0; r1 = v1 * v1; r2 = v2 * v2; r3 = v3 * v3;
      r4 = v4 * v4; r5 = v5 * v5; r6 = v6 * v6; r7 = v7 * v7;
    }
#pragma unroll
    for (int i = 8; i < 64; i += 8) {
      float v0 = row[i + 0], v1 = row[i + 1], v2 = row[i + 2], v3 = row[i + 3];
      float v4 = row[i + 4], v5 = row[i + 5], v6 = row[i + 6], v7 = row[i + 7];
      r0 = r0 + v0 * v0; r1 = r1 + v1 * v1; r2 = r2 + v2 * v2; r3 = r3 + v3 * v3;
      r4 = r4 + v4 * v4; r5 = r5 + v5 * v5; r6 = r6 + v6 * v6; r7 = r7 + v7 * v7;
    }
    s = ((r0 + r1) + (r2 + r3)) + ((r4 + r5) + (r6 + r7));
  }
  e2[k] = s;
  e2b[k] = s + 32.0f;
}

// ---------------------------------------------------------------------------
// K1b: bf16 hi/lo split image, fully coalesced. Row layout: 8 granules of
// 16 B; logical granule g stored at physical ((g + r) & 7) -> conflict-lean
// wave reads AND linear staging copies.
// ---------------------------------------------------------------------------
__global__ void img_kernel(const float* __restrict__ cb, char* __restrict__ img) {
  int t = blockIdx.x * 256 + threadIdx.x;   // 65536 threads, 4 elements each
  int k  = t >> 4;
  int d0 = (t & 15) * 4;
  float4 f = ((const float4*)cb)[t];
  ushort4 hi, lo;
  hi.x = f2bf(f.x); lo.x = f2bf(f.x - bf2f(hi.x));
  hi.y = f2bf(f.y); lo.y = f2bf(f.y - bf2f(hi.y));
  hi.z = f2bf(f.z); lo.z = f2bf(f.z - bf2f(hi.z));
  hi.w = f2bf(f.w); lo.w = f2bf(f.w - bf2f(hi.w));
  int c = k >> 7, r = k & 127;
  int g = d0 >> 3;
  int off = ((g + r) & 7) * 16 + (d0 & 7) * 2;
  char* base = img + (size_t)c * CH_BYTES + r * 128;
  *(ushort4*)(base + off) = hi;
  *(ushort4*)(base + CH_LO + off) = lo;
}

// ---------------------------------------------------------------------------
// K2: MFMA distance pass. 512 threads = 8 waves x 64 rows = 512 rows/block;
// K-split 4 (1024 codes/block). val = (e2+32) - 2 z.e via 3 bf16-split
// products, e2 as read-only MFMA C operand. key = (bits&~0xFF)|tile;
// top-2/elem via min+med3; per-row top-4-of-32 in two 256-row passes
// (cand stride 33 dwords -> conflict-free reduction reads).
// ---------------------------------------------------------------------------
__global__ __launch_bounds__(512, 4)
void vq_mfma_kernel(const float* __restrict__ z_e,
                    const char* __restrict__ img,
                    const float* __restrict__ e2b,
                    unsigned int* __restrict__ cands) {
  __shared__ union {
    uint4 q[CH_QUADS];
    char raw[CH_BYTES];
    unsigned int cand[256 * 33];     // 33792 B
  } sm;
  __shared__ float lds_e2[128];
  const int tid  = threadIdx.x;
  const int wave = tid >> 6, lane = tid & 63;
  const int quad = lane >> 4, c16 = lane & 15;
  const int rb   = blockIdx.x >> 2;           // row-group of 512
  const int sp   = blockIdx.x & 3;            // K-split id
  const int mb   = rb * 512 + wave * 64;

  // A-fragments: 4 row-tiles x (k-halves) x (hi/lo), A[m=lane&15][k=quad*8+j]
  s16x8 zh[4][2], zl[4][2];
#pragma unroll
  for (int mt = 0; mt < 4; ++mt) {
    int m = mb + mt * 16 + c16;
#pragma unroll
    for (int s = 0; s < 2; ++s) {
      const float* zp = z_e + (size_t)m * 64 + s * 32 + quad * 8;
      float4 fa = ((const float4*)zp)[0];
      float4 fb = ((const float4*)zp)[1];
      float v[8] = {fa.x, fa.y, fa.z, fa.w, fb.x, fb.y, fb.z, fb.w};
      union { s16x8 v8; unsigned short e[8]; } H, L;
#pragma unroll
      for (int j = 0; j < 8; ++j) {
        float f = -2.0f * v[j];
        unsigned short h = f2bf(f);
        H.e[j] = h;
        L.e[j] = f2bf(f - bf2f(h));
      }
      zh[mt][s] = H.v8;
      zl[mt][s] = L.v8;
    }
  }

  unsigned int b1[4][4], b2[4][4];
#pragma unroll
  for (int mt = 0; mt < 4; ++mt)
#pragma unroll
    for (int r = 0; r < 4; ++r) { b1[mt][r] = 0xFFFFFFFFu; b2[mt][r] = 0xFFFFFFFFu; }

  const int swz0 = ((quad + c16) & 7) * 16;       // t-invariant swizzle offsets
  const int swz1 = ((quad + 4 + c16) & 7) * 16;

  for (int c = 0; c < NCHB; ++c) {
    __syncthreads();
    {
      const uint4* src = (const uint4*)(img + (size_t)(sp * NCHB + c) * CH_BYTES);
#pragma unroll
      for (int i = 0; i < 4; ++i) sm.q[tid + i * 512] = src[tid + i * 512];
      if (tid < 128) lds_e2[tid] = e2b[sp * 1024 + c * 128 + tid];
    }
    __syncthreads();

#pragma unroll 1
    for (int t = 0; t < 8; ++t) {
      const char* hb = sm.raw + (t * 16 + c16) * 128;
      s16x8 Bh0 = *(const s16x8*)(hb + swz0);
      s16x8 Bh1 = *(const s16x8*)(hb + swz1);
      s16x8 Bl0 = *(const s16x8*)(hb + CH_LO + swz0);
      s16x8 Bl1 = *(const s16x8*)(hb + CH_LO + swz1);
      float e2v = lds_e2[t * 16 + c16];
      unsigned int tid8 = (unsigned int)(sp * 64 + c * 8 + t);  // global 16-code tile id
      f32x4 cvec = {e2v, e2v, e2v, e2v};

#pragma unroll
      for (int mt = 0; mt < 4; ++mt) {
        f32x4 acc;
        acc = __builtin_amdgcn_mfma_f32_16x16x32_bf16(zh[mt][0], Bh0, cvec, 0, 0, 0);
        acc = __builtin_amdgcn_mfma_f32_16x16x32_bf16(zh[mt][1], Bh1, acc, 0, 0, 0);
        acc = __builtin_amdgcn_mfma_f32_16x16x32_bf16(zl[mt][0], Bh0, acc, 0, 0, 0);
        acc = __builtin_amdgcn_mfma_f32_16x16x32_bf16(zl[mt][1], Bh1, acc, 0, 0, 0);
        acc = __builtin_amdgcn_mfma_f32_16x16x32_bf16(zh[mt][0], Bl0, acc, 0, 0, 0);
        acc = __builtin_amdgcn_mfma_f32_16x16x32_bf16(zh[mt][1], Bl1, acc, 0, 0, 0);
#pragma unroll
        for (int r = 0; r < 4; ++r) {
          unsigned int key = (__float_as_uint(acc[r]) & 0xFFFFFF00u) | tid8;
          b2[mt][r] = med3_u32(b1[mt][r], b2[mt][r], key);
          b1[mt][r] = umin_(b1[mt][r], key);
        }
      }
    }
  }

  // final selection: two passes of 256 rows through the cand buffer
  for (int pass = 0; pass < 2; ++pass) {
    __syncthreads();
    if ((wave >> 2) == pass) {
      int wl = wave & 3;
#pragma unroll
      for (int mt = 0; mt < 4; ++mt)
#pragma unroll
        for (int r = 0; r < 4; ++r) {
          int lr = wl * 64 + mt * 16 + quad * 4 + r;   // C: col=lane&15, row=quad*4+reg
          sm.cand[lr * 33 + c16 * 2 + 0] = b1[mt][r];
          sm.cand[lr * 33 + c16 * 2 + 1] = b2[mt][r];
        }
    }
    __syncthreads();
    if (tid < 256) {
      unsigned int kk[4] = {0xFFFFFFFFu, 0xFFFFFFFFu, 0xFFFFFFFFu, 0xFFFFFFFFu};
      unsigned int vv[4] = {0, 0, 0, 0};
      for (int j = 0; j < 32; ++j) {
        unsigned int key = sm.cand[tid * 33 + j];
        if (key < kk[3]) {
          kk[3] = key;
          vv[3] = (key & 0xFFu) * 16 + (unsigned int)(j >> 1);  // k = tile*16 + col
          for (int p = 3; p > 0; --p)
            if (kk[p] < kk[p - 1]) {
              unsigned int a = kk[p]; kk[p] = kk[p - 1]; kk[p - 1] = a;
              unsigned int b = vv[p]; vv[p] = vv[p - 1]; vv[p - 1] = b;
            }
        }
      }
      int grow = rb * 512 + pass * 256 + tid;
#pragma unroll
      for (int i = 0; i < 4; ++i) cands[grow * 16 + sp * 4 + i] = vv[i];
    }
  }
}

// ---------------------------------------------------------------------------
// K3: exact re-check of 16 candidates/row, 16 lanes per row (one cand each).
// z rows staged once in LDS. numpy-exact formula, first-min tie-break.
// Writes idx + z_q_st (+ z_q when write_zq) + loss accum.
// ---------------------------------------------------------------------------
__global__ __launch_bounds__(256)
void exact_pick_kernel(const float* __restrict__ z_e, const float* __restrict__ cb,
                       const float* __restrict__ e2, const unsigned int* __restrict__ cands,
                       float* __restrict__ out, double* __restrict__ accum, int write_zq) {
  __shared__ float lds_z[16 * 68];
  __shared__ double lds_red[4];
  const int tid = threadIdx.x;
  const int rl  = tid >> 4;                       // row local 0..15
  const int j   = tid & 15;                       // candidate slot / element group
  const int r   = blockIdx.x * 16 + rl;           // global row

  {
    float4 v = ((const float4*)z_e)[(size_t)blockIdx.x * 256 + tid];
    *(float4*)&lds_z[(tid >> 4) * 68 + (tid & 15) * 4] = v;
  }
  __syncthreads();

  const float* zrow = &lds_z[rl * 68];
  float4 z4[16];
#pragma unroll
  for (int i = 0; i < 16; ++i) z4[i] = *(const float4*)&zrow[i * 4];

  float z2;
  {
#pragma clang fp contract(off)
    float4 R0 = make_float4(0.f, 0.f, 0.f, 0.f);
    float4 R1 = make_float4(0.f, 0.f, 0.f, 0.f);
#pragma unroll
    for (int a = 0; a < 16; a += 2) {
      R0.x = R0.x + z4[a].x * z4[a].x;
      R0.y = R0.y + z4[a].y * z4[a].y;
      R0.z = R0.z + z4[a].z * z4[a].z;
      R0.w = R0.w + z4[a].w * z4[a].w;
      R1.x = R1.x + z4[a + 1].x * z4[a + 1].x;
      R1.y = R1.y + z4[a + 1].y * z4[a + 1].y;
      R1.z = R1.z + z4[a + 1].z * z4[a + 1].z;
      R1.w = R1.w + z4[a + 1].w * z4[a + 1].w;
    }
    z2 = ((R0.x + R0.y) + (R0.z + R0.w)) + ((R1.x + R1.y) + (R1.z + R1.w));
  }

  int k = (int)cands[(size_t)r * 16 + j];
  float d;
  {
    const float4* ev = (const float4*)(cb + (size_t)k * 64);
    float4 a0 = make_float4(0.f, 0.f, 0.f, 0.f);
    float4 a1 = make_float4(0.f, 0.f, 0.f, 0.f);
    float4 a2 = make_float4(0.f, 0.f, 0.f, 0.f);
    float4 a3 = make_float4(0.f, 0.f, 0.f, 0.f);
#pragma unroll
    for (int q = 0; q < 4; ++q) {
      float4 e0 = ev[4 * q + 0], e1 = ev[4 * q + 1], e2v = ev[4 * q + 2], e3 = ev[4 * q + 3];
      a0.x = fmaf(z4[4 * q + 0].x, e0.x, a0.x); a0.y = fmaf(z4[4 * q + 0].y, e0.y, a0.y);
      a0.z = fmaf(z4[4 * q + 0].z, e0.z, a0.z); a0.w = fmaf(z4[4 * q + 0].w, e0.w, a0.w);
      a1.x = fmaf(z4[4 * q + 1].x, e1.x, a1.x); a1.y = fmaf(z4[4 * q + 1].y, e1.y, a1.y);
      a1.z = fmaf(z4[4 * q + 1].z, e1.z, a1.z); a1.w = fmaf(z4[4 * q + 1].w, e1.w, a1.w);
      a2.x = fmaf(z4[4 * q + 2].x, e2v.x, a2.x); a2.y = fmaf(z4[4 * q + 2].y, e2v.y, a2.y);
      a2.z = fmaf(z4[4 * q + 2].z, e2v.z, a2.z); a2.w = fmaf(z4[4 * q + 2].w, e2v.w, a2.w);
      a3.x = fmaf(z4[4 * q + 3].x, e3.x, a3.x); a3.y = fmaf(z4[4 * q + 3].y, e3.y, a3.y);
      a3.z = fmaf(z4[4 * q + 3].z, e3.z, a3.z); a3.w = fmaf(z4[4 * q + 3].w, e3.w, a3.w);
    }
    {
#pragma clang fp contract(off)
      float sx = (a0.x + a1.x) + (a2.x + a3.x);
      float sy = (a0.y + a1.y) + (a2.y + a3.y);
      float sz = (a0.z + a1.z) + (a2.z + a3.z);
      float sw = (a0.w + a1.w) + (a2.w + a3.w);
      float dot = (sx + sy) + (sz + sw);
      float tt = z2 + e2[k];
      d = tt - 2.0f * dot;
    }
  }

  // min over 16 lanes, tie -> smaller k (numpy first-occurrence)
#pragma unroll
  for (int off = 8; off > 0; off >>= 1) {
    float d2 = __shfl_down(d, off, 16);
    int   k2 = __shfl_down(k, off, 16);
    if (d2 < d || (d2 == d && k2 < k)) { d = d2; k = k2; }
  }
  int bk = __shfl(k, 0, 16);

  if (j == 0) out[OFF_IDX + r] = (float)bk;

  float4 q  = ((const float4*)(cb + (size_t)bk * 64))[j];
  float4 zv = *(const float4*)&zrow[j * 4];
  ((float4*)(out + (size_t)r * 64))[j] = q;
  if (write_zq) {
    float* dst = out + OFF_ZQ + (size_t)r * 64 + j * 4;   // 8B aligned
    ((float2*)dst)[0] = make_float2(q.x, q.y);
    ((float2*)dst)[1] = make_float2(q.z, q.w);
  }
  double csum;
  {
    float dx = zv.x - q.x, dy = zv.y - q.y, dz = zv.z - q.z, dw = zv.w - q.w;
    csum = (double)dx * dx + (double)dy * dy + (double)dz * dz + (double)dw * dw;
  }
#pragma unroll
  for (int off = 32; off > 0; off >>= 1) csum += __shfl_down(csum, off);
  if ((tid & 63) == 0) lds_red[tid >> 6] = csum;
  __syncthreads();
  if (tid == 0)
    atomicAdd(accum, (lds_red[0] + lds_red[1]) + (lds_red[2] + lds_red[3]));
}

// ---------------------------------------------------------------------------
// K4 (fallback only): z_q <- z_q_st; overwrites cand scratch in z_q region.
// ---------------------------------------------------------------------------
__global__ void copy_zq_kernel(float* __restrict__ out) {
  size_t t = (size_t)blockIdx.x * 256 + threadIdx.x;
  float4 v = ((const float4*)out)[t];
  float* dst = out + OFF_ZQ + t * 4;
  ((float2*)dst)[0] = make_float2(v.x, v.y);
  ((float2*)dst)[1] = make_float2(v.z, v.w);
}

// ---------------------------------------------------------------------------
// K5: vq_loss + perplexity
// ---------------------------------------------------------------------------
__global__ void finalize_kernel(const float* __restrict__ ema,
                                const double* __restrict__ accum,
                                float* __restrict__ out) {
  __shared__ double red[256];
  const int t = threadIdx.x;

  double s = 0.0;
  for (int i = t; i < K_CODES; i += 256) s += (double)(ema[i] + 1e-10f);
  red[t] = s;
  __syncthreads();
  for (int off = 128; off > 0; off >>= 1) {
    if (t < off) red[t] += red[t + off];
    __syncthreads();
  }
  double S = red[0];
  __syncthreads();

  double h = 0.0;
  for (int i = t; i < K_CODES; i += 256) {
    float p = (float)((ema[i] + 1e-10f) / (float)S);
    h += (double)(p * logf(p));
  }
  red[t] = h;
  __syncthreads();
  for (int off = 128; off > 0; off >>= 1) {
    if (t < off) red[t] += red[t + off];
    __syncthreads();
  }

  if (t == 0) {
    out[OFF_SCAL]     = 0.25f * (float)(accum[0] / (double)((size_t)M_ROWS * (size_t)D_DIM));
    out[OFF_SCAL + 1] = expf((float)(-red[0]));
  }
}

extern "C" void kernel_launch(void* const* d_in, const int* in_sizes, int n_in,
                              void* d_out, int out_size, void* d_ws, size_t ws_size,
                              hipStream_t stream) {
  (void)in_sizes; (void)n_in; (void)out_size;
  const float* z_e = (const float*)d_in[0];
  const float* cb  = (const float*)d_in[1];
  const float* ema = (const float*)d_in[2];
  float* out = (float*)d_out;

  double* accum = (double*)d_ws;                            // 8 B used, 256 B zeroed
  float* e2     = (float*)((char*)d_ws + 256);              // 16 KB
  char*  img    = (char*)d_out + IMG_OFF;                   // 1 MB scratch in z_q_st region
  float* e2b    = (float*)((char*)d_out + E2B_OFF);         // 16 KB scratch

  const size_t cand_bytes = (size_t)M_ROWS * 16 * 4;        // 4 MB
  const int use_ws = (ws_size >= 32768 + cand_bytes) ? 1 : 0;
  unsigned int* cands = use_ws
      ? (unsigned int*)((char*)d_ws + 32768)
      : (unsigned int*)((char*)d_out + CANDB_OFF);          // z_q region, needs copy pass

  (void)hipMemsetAsync(d_ws, 0, 256, stream);
  e2_kernel<<<K_CODES / 256, 256, 0, stream>>>(cb, e2, e2b);
  img_kernel<<<(K_CODES * D_DIM / 4) / 256, 256, 0, stream>>>(cb, img);
  vq_mfma_kernel<<<(M_ROWS / 512) * NSPLIT, 512, 0, stream>>>(z_e, img, e2b, cands);
  exact_pick_kernel<<<M_ROWS / 16, 256, 0, stream>>>(z_e, cb, e2, cands, out, accum, use_ws);
  if (!use_ws)
    copy_zq_kernel<<<(M_ROWS * D_DIM / 4) / 256, 256, 0, stream>>>(out);
  finalize_kernel<<<1, 256, 0, stream>>>(ema, accum, out);
}